// Round 1
// baseline (326.112 us; speedup 1.0000x reference)
//
#include <hip/hip_runtime.h>
#include <hip/hip_bf16.h>
#include <stdint.h>

#define D_IN   1024
#define D_OUT  1024
#define NHEAD  16
#define HDIM   64
#define SEQ    2048
#define BATCH  2
#define M_TOT  (BATCH*SEQ)   // 4096

typedef __attribute__((ext_vector_type(8))) short bfx8;   // 8 bf16 (4 VGPRs)
typedef __attribute__((ext_vector_type(4))) float fx4;    // 4 f32 acc
typedef unsigned short u16;
typedef unsigned int   u32;

__device__ __forceinline__ u16 f2bf(float f) {
    u32 u = __builtin_bit_cast(u32, f);
    u32 r = (u + 0x7FFFu + ((u >> 16) & 1u)) >> 16;   // RNE
    return (u16)r;
}

// ---------------- x fp32 -> bf16 ----------------
__global__ void k_conv_x(const float* __restrict__ x, u16* __restrict__ xb) {
    int i = blockIdx.x * 256 + threadIdx.x;           // 524288 threads, 8 floats each
    const float4* s = reinterpret_cast<const float4*>(x);
    float4 a = s[2*i], b = s[2*i+1];
    uint4 o;
    o.x = (u32)f2bf(a.x) | ((u32)f2bf(a.y) << 16);
    o.y = (u32)f2bf(a.z) | ((u32)f2bf(a.w) << 16);
    o.z = (u32)f2bf(b.x) | ((u32)f2bf(b.y) << 16);
    o.w = (u32)f2bf(b.z) | ((u32)f2bf(b.w) << 16);
    reinterpret_cast<uint4*>(xb)[i] = o;
}

// ------------- W fp32 -> bf16, transposed (Wt[n][k] = W[k][n]) -------------
__global__ void k_conv_wt(const float* __restrict__ Wq, const float* __restrict__ Wk,
                          const float* __restrict__ Wv, const float* __restrict__ Wo,
                          u16* __restrict__ wt) {
    __shared__ float tile[32][33];
    int wsel = blockIdx.z;
    const float* W = (wsel == 0) ? Wq : (wsel == 1) ? Wk : (wsel == 2) ? Wv : Wo;
    u16* dst = wt + (size_t)wsel * D_IN * D_OUT;
    int r0 = blockIdx.y * 32, c0 = blockIdx.x * 32;
    int tx = threadIdx.x & 31, ty = threadIdx.x >> 5;  // ty 0..7
    #pragma unroll
    for (int k = 0; k < 4; k++) {
        int i = ty + k * 8;
        tile[i][tx] = W[(size_t)(r0 + i) * D_OUT + c0 + tx];
    }
    __syncthreads();
    #pragma unroll
    for (int k = 0; k < 4; k++) {
        int i = ty + k * 8;
        dst[(size_t)(c0 + i) * D_IN + r0 + tx] = f2bf(tile[tx][i]);
    }
}

// ---------------- QKV projection GEMM ----------------
// A = xb [4096][1024] bf16, Bt = wt (3 x [1024 n][1024 k]) bf16.
// Output per proj: [b][h][s][d] bf16.
__global__ __launch_bounds__(256) void k_qkv(const u16* __restrict__ xb,
                                             const u16* __restrict__ wt,
                                             u16* __restrict__ qkv) {
    __shared__ u16 aL[64][32];
    __shared__ u16 bL[64][32];
    const int K = D_IN;
    int proj = blockIdx.z;
    const u16* bt = wt + (size_t)proj * K * D_OUT;
    u16* outp = qkv + (size_t)proj * (size_t)M_TOT * D_OUT;
    int nb = blockIdx.x * 64, mb = blockIdx.y * 64;
    int t = threadIdx.x, lane = t & 63, w = t >> 6;
    int lg = lane >> 4, li = lane & 15;
    int srow = t >> 2, schunk = (t & 3) * 8;
    fx4 acc[4] = {{0,0,0,0},{0,0,0,0},{0,0,0,0},{0,0,0,0}};
    for (int kb = 0; kb < K; kb += 32) {
        *reinterpret_cast<bfx8*>(&aL[srow][schunk]) =
            *reinterpret_cast<const bfx8*>(&xb[(size_t)(mb + srow) * K + kb + schunk]);
        *reinterpret_cast<bfx8*>(&bL[srow][schunk]) =
            *reinterpret_cast<const bfx8*>(&bt[(size_t)(nb + srow) * K + kb + schunk]);
        __syncthreads();
        bfx8 af = *reinterpret_cast<const bfx8*>(&aL[w * 16 + li][lg * 8]);
        #pragma unroll
        for (int tt = 0; tt < 4; tt++) {
            bfx8 bf = *reinterpret_cast<const bfx8*>(&bL[tt * 16 + li][lg * 8]);
            acc[tt] = __builtin_amdgcn_mfma_f32_16x16x32_bf16(af, bf, acc[tt], 0, 0, 0);
        }
        __syncthreads();
    }
    int rbase = mb + w * 16 + lg * 4;
    #pragma unroll
    for (int tt = 0; tt < 4; tt++) {
        int n = nb + tt * 16 + li;
        int h = n >> 6, d = n & 63;
        #pragma unroll
        for (int r = 0; r < 4; r++) {
            int m = rbase + r;
            int b = m >> 11, s = m & 2047;
            outp[(((size_t)(b * NHEAD + h)) * SEQ + s) * HDIM + d] = f2bf(acc[tt][r]);
        }
    }
}

// ---------------- causal flash attention ----------------
// Q,K,V: [b*h][s][d] bf16 -> ctx [b][s][h*64+d] bf16
__global__ __launch_bounds__(256) void k_attn(const u16* __restrict__ qkv,
                                              u16* __restrict__ ctx) {
    __shared__ u16 kL[32][HDIM];       // K tile  [kv][d]
    __shared__ u16 vtL[HDIM][32];      // V tile transposed [d][kv]
    __shared__ u16 pL[4][16][32];      // per-wave P tile [q][kv]
    const u16* Q  = qkv;
    const u16* Kp = qkv + (size_t)M_TOT * D_OUT;
    const u16* Vp = Kp + (size_t)M_TOT * D_OUT;
    int bh = blockIdx.y;
    int qb = blockIdx.x * 64;
    const size_t base = (size_t)bh * SEQ * HDIM;
    int t = threadIdx.x, lane = t & 63, w = t >> 6;
    int lg = lane >> 4, li = lane & 15;
    int qrow = qb + w * 16 + li;
    bfx8 qf0 = *reinterpret_cast<const bfx8*>(&Q[base + (size_t)qrow * HDIM + lg * 8]);
    bfx8 qf1 = *reinterpret_cast<const bfx8*>(&Q[base + (size_t)qrow * HDIM + 32 + lg * 8]);
    fx4 cacc[4] = {{0,0,0,0},{0,0,0,0},{0,0,0,0},{0,0,0,0}};
    float mrow[4], lrow[4];
    #pragma unroll
    for (int r = 0; r < 4; r++) { mrow[r] = -__builtin_inff(); lrow[r] = 0.f; }
    int qlast = qb + w * 16 + 15;
    int nkv = (qb + 64) / 32;
    int srow = t >> 3, schunk = (t & 7) * 8;
    for (int ib = 0; ib < nkv; ib++) {
        int kvb = ib * 32;
        // stage K tile and transposed V tile
        *reinterpret_cast<bfx8*>(&kL[srow][schunk]) =
            *reinterpret_cast<const bfx8*>(&Kp[base + (size_t)(kvb + srow) * HDIM + schunk]);
        bfx8 vv = *reinterpret_cast<const bfx8*>(&Vp[base + (size_t)(kvb + srow) * HDIM + schunk]);
        #pragma unroll
        for (int j = 0; j < 8; j++) vtL[schunk + j][srow] = (u16)vv[j];
        __syncthreads();
        if (kvb <= qlast) {
            fx4 sc[2];
            #pragma unroll
            for (int nt = 0; nt < 2; nt++) {
                bfx8 kf0 = *reinterpret_cast<const bfx8*>(&kL[nt * 16 + li][lg * 8]);
                bfx8 kf1 = *reinterpret_cast<const bfx8*>(&kL[nt * 16 + li][32 + lg * 8]);
                fx4 z = {0, 0, 0, 0};
                z = __builtin_amdgcn_mfma_f32_16x16x32_bf16(qf0, kf0, z, 0, 0, 0);
                z = __builtin_amdgcn_mfma_f32_16x16x32_bf16(qf1, kf1, z, 0, 0, 0);
                sc[nt] = z;
            }
            int q0 = qb + w * 16 + lg * 4;
            #pragma unroll
            for (int nt = 0; nt < 2; nt++) {
                int kvg = kvb + nt * 16 + li;
                #pragma unroll
                for (int r = 0; r < 4; r++) {
                    float s = sc[nt][r] * 0.125f;
                    sc[nt][r] = (kvg > q0 + r) ? -__builtin_inff() : s;
                }
            }
            float corr[4], psum[4];
            #pragma unroll
            for (int r = 0; r < 4; r++) {
                float v = fmaxf(sc[0][r], sc[1][r]);
                v = fmaxf(v, __shfl_xor(v, 1));
                v = fmaxf(v, __shfl_xor(v, 2));
                v = fmaxf(v, __shfl_xor(v, 4));
                v = fmaxf(v, __shfl_xor(v, 8));
                float mn = fmaxf(mrow[r], v);
                corr[r] = __expf(mrow[r] - mn);   // m=-inf first time -> 0
                mrow[r] = mn;
                psum[r] = 0.f;
            }
            #pragma unroll
            for (int nt = 0; nt < 2; nt++) {
                #pragma unroll
                for (int r = 0; r < 4; r++) {
                    float p = __expf(sc[nt][r] - mrow[r]);  // exp(-inf)=0 for masked
                    psum[r] += p;
                    pL[w][lg * 4 + r][nt * 16 + li] = f2bf(p);
                }
            }
            #pragma unroll
            for (int r = 0; r < 4; r++) {
                float v = psum[r];
                v += __shfl_xor(v, 1);
                v += __shfl_xor(v, 2);
                v += __shfl_xor(v, 4);
                v += __shfl_xor(v, 8);
                lrow[r] = lrow[r] * corr[r] + v;
                #pragma unroll
                for (int dt = 0; dt < 4; dt++) cacc[dt][r] *= corr[r];
            }
            // wave-synchronous P handoff through LDS (same wave wrote it)
            asm volatile("" ::: "memory");
            __builtin_amdgcn_wave_barrier();
            bfx8 pf = *reinterpret_cast<const bfx8*>(&pL[w][li][lg * 8]);
            #pragma unroll
            for (int dt = 0; dt < 4; dt++) {
                bfx8 vf = *reinterpret_cast<const bfx8*>(&vtL[dt * 16 + li][lg * 8]);
                cacc[dt] = __builtin_amdgcn_mfma_f32_16x16x32_bf16(pf, vf, cacc[dt], 0, 0, 0);
            }
        }
        __syncthreads();
    }
    int b = bh >> 4, h = bh & 15;
    #pragma unroll
    for (int dt = 0; dt < 4; dt++) {
        #pragma unroll
        for (int r = 0; r < 4; r++) {
            int q = qb + w * 16 + lg * 4 + r;
            float v = cacc[dt][r] / lrow[r];
            ctx[((size_t)(b * SEQ + q)) * D_OUT + h * HDIM + dt * 16 + li] = f2bf(v);
        }
    }
}

// ---------------- output projection + bias ----------------
__global__ __launch_bounds__(256) void k_oproj(const u16* __restrict__ cb,
                                               const u16* __restrict__ wot,
                                               const float* __restrict__ bo,
                                               float* __restrict__ out) {
    __shared__ u16 aL[64][32];
    __shared__ u16 bL[64][32];
    const int K = D_OUT;
    int nb = blockIdx.x * 64, mb = blockIdx.y * 64;
    int t = threadIdx.x, lane = t & 63, w = t >> 6;
    int lg = lane >> 4, li = lane & 15;
    int srow = t >> 2, schunk = (t & 3) * 8;
    fx4 acc[4] = {{0,0,0,0},{0,0,0,0},{0,0,0,0},{0,0,0,0}};
    for (int kb = 0; kb < K; kb += 32) {
        *reinterpret_cast<bfx8*>(&aL[srow][schunk]) =
            *reinterpret_cast<const bfx8*>(&cb[(size_t)(mb + srow) * K + kb + schunk]);
        *reinterpret_cast<bfx8*>(&bL[srow][schunk]) =
            *reinterpret_cast<const bfx8*>(&wot[(size_t)(nb + srow) * K + kb + schunk]);
        __syncthreads();
        bfx8 af = *reinterpret_cast<const bfx8*>(&aL[w * 16 + li][lg * 8]);
        #pragma unroll
        for (int tt = 0; tt < 4; tt++) {
            bfx8 bf = *reinterpret_cast<const bfx8*>(&bL[tt * 16 + li][lg * 8]);
            acc[tt] = __builtin_amdgcn_mfma_f32_16x16x32_bf16(af, bf, acc[tt], 0, 0, 0);
        }
        __syncthreads();
    }
    int rbase = mb + w * 16 + lg * 4;
    #pragma unroll
    for (int tt = 0; tt < 4; tt++) {
        int n = nb + tt * 16 + li;
        float bias = bo[n];
        #pragma unroll
        for (int r = 0; r < 4; r++) {
            int m = rbase + r;
            out[(size_t)m * D_OUT + n] = acc[tt][r] + bias;
        }
    }
}

extern "C" void kernel_launch(void* const* d_in, const int* in_sizes, int n_in,
                              void* d_out, int out_size, void* d_ws, size_t ws_size,
                              hipStream_t stream) {
    const float* x  = (const float*)d_in[0];
    const float* Wq = (const float*)d_in[1];
    const float* Wk = (const float*)d_in[2];
    const float* Wv = (const float*)d_in[3];
    const float* Wo = (const float*)d_in[4];
    const float* bo = (const float*)d_in[5];
    float* out = (float*)d_out;

    char* ws = (char*)d_ws;
    u16* xb   = (u16*)(ws);                    //  8 MiB: x bf16 [4096][1024]
    u16* wt   = (u16*)(ws + (8u << 20));       //  8 MiB: Wq,Wk,Wv,Wo transposed bf16
    u16* qkvb = (u16*)(ws + (16u << 20));      // 24 MiB: Q,K,V [b][h][s][d] bf16
    u16* ctxb = (u16*)(ws + (40u << 20));      //  8 MiB: ctx [b][s][h*d] bf16

    k_conv_x <<<2048, 256, 0, stream>>>(x, xb);
    k_conv_wt<<<dim3(32, 32, 4), 256, 0, stream>>>(Wq, Wk, Wv, Wo, wt);
    k_qkv    <<<dim3(D_OUT / 64, M_TOT / 64, 3), 256, 0, stream>>>(xb, wt, qkvb);
    k_attn   <<<dim3(SEQ / 64, BATCH * NHEAD), 256, 0, stream>>>(qkvb, ctxb);
    k_oproj  <<<dim3(D_OUT / 64, M_TOT / 64), 256, 0, stream>>>(
        ctxb, wt + (size_t)3 * D_IN * D_OUT, bo, out);
}

// Round 2
// 163.103 us; speedup vs baseline: 1.9994x; 1.9994x over previous
//
#include <hip/hip_runtime.h>
#include <hip/hip_bf16.h>
#include <stdint.h>

#define D_IN   1024
#define D_OUT  1024
#define NHEAD  16
#define HDIM   64
#define SEQ    2048
#define BATCH  2
#define M_TOT  (BATCH*SEQ)   // 4096

typedef __attribute__((ext_vector_type(8)))  short bfx8;   // 8 bf16
typedef __attribute__((ext_vector_type(4)))  short bfx4;   // 4 bf16
typedef __attribute__((ext_vector_type(4)))  float fx4;
typedef __attribute__((ext_vector_type(16))) float fx16;
typedef unsigned short u16;
typedef unsigned int   u32;

__device__ __forceinline__ u16 f2bf(float f) {
    u32 u = __builtin_bit_cast(u32, f);
    u32 r = (u + 0x7FFFu + ((u >> 16) & 1u)) >> 16;   // RNE
    return (u16)r;
}

__device__ __forceinline__ u32 cvtpk(float lo, float hi) {
    u32 r;
    asm("v_cvt_pk_bf16_f32 %0, %1, %2" : "=v"(r) : "v"(lo), "v"(hi));
    return r;
}

__device__ __forceinline__ bfx8 ld8(const u16* p) {      // two 8B LDS reads
    bfx4 a = *reinterpret_cast<const bfx4*>(p);
    bfx4 b = *reinterpret_cast<const bfx4*>(p + 4);
    bfx8 r = {a[0], a[1], a[2], a[3], b[0], b[1], b[2], b[3]};
    return r;
}

// ---------------- x fp32 -> bf16 ----------------
__global__ void k_conv_x(const float* __restrict__ x, u16* __restrict__ xb) {
    int i = blockIdx.x * 256 + threadIdx.x;
    const float4* s = reinterpret_cast<const float4*>(x);
    float4 a = s[2*i], b = s[2*i+1];
    uint4 o;
    o.x = (u32)f2bf(a.x) | ((u32)f2bf(a.y) << 16);
    o.y = (u32)f2bf(a.z) | ((u32)f2bf(a.w) << 16);
    o.z = (u32)f2bf(b.x) | ((u32)f2bf(b.y) << 16);
    o.w = (u32)f2bf(b.z) | ((u32)f2bf(b.w) << 16);
    reinterpret_cast<uint4*>(xb)[i] = o;
}

// ------------- W fp32 -> bf16, transposed (Wt[n][k] = W[k][n]) -------------
__global__ void k_conv_wt(const float* __restrict__ Wq, const float* __restrict__ Wk,
                          const float* __restrict__ Wv, const float* __restrict__ Wo,
                          u16* __restrict__ wt) {
    __shared__ float tile[32][33];
    int wsel = blockIdx.z;
    const float* W = (wsel == 0) ? Wq : (wsel == 1) ? Wk : (wsel == 2) ? Wv : Wo;
    u16* dst = wt + (size_t)wsel * D_IN * D_OUT;
    int r0 = blockIdx.y * 32, c0 = blockIdx.x * 32;
    int tx = threadIdx.x & 31, ty = threadIdx.x >> 5;
    #pragma unroll
    for (int k = 0; k < 4; k++) {
        int i = ty + k * 8;
        tile[i][tx] = W[(size_t)(r0 + i) * D_OUT + c0 + tx];
    }
    __syncthreads();
    #pragma unroll
    for (int k = 0; k < 4; k++) {
        int i = ty + k * 8;
        dst[(size_t)(c0 + i) * D_IN + r0 + tx] = f2bf(tile[tx][i]);
    }
}

// ---------------- QKV projection GEMM ----------------
__global__ __launch_bounds__(256) void k_qkv(const u16* __restrict__ xb,
                                             const u16* __restrict__ wt,
                                             u16* __restrict__ qkv) {
    __shared__ u16 aL[64][32];
    __shared__ u16 bL[64][32];
    const int K = D_IN;
    int proj = blockIdx.z;
    const u16* bt = wt + (size_t)proj * K * D_OUT;
    u16* outp = qkv + (size_t)proj * (size_t)M_TOT * D_OUT;
    int nb = blockIdx.x * 64, mb = blockIdx.y * 64;
    int t = threadIdx.x, lane = t & 63, w = t >> 6;
    int lg = lane >> 4, li = lane & 15;
    int srow = t >> 2, schunk = (t & 3) * 8;
    fx4 acc[4] = {{0,0,0,0},{0,0,0,0},{0,0,0,0},{0,0,0,0}};
    for (int kb = 0; kb < K; kb += 32) {
        *reinterpret_cast<bfx8*>(&aL[srow][schunk]) =
            *reinterpret_cast<const bfx8*>(&xb[(size_t)(mb + srow) * K + kb + schunk]);
        *reinterpret_cast<bfx8*>(&bL[srow][schunk]) =
            *reinterpret_cast<const bfx8*>(&bt[(size_t)(nb + srow) * K + kb + schunk]);
        __syncthreads();
        bfx8 af = *reinterpret_cast<const bfx8*>(&aL[w * 16 + li][lg * 8]);
        #pragma unroll
        for (int tt = 0; tt < 4; tt++) {
            bfx8 bf = *reinterpret_cast<const bfx8*>(&bL[tt * 16 + li][lg * 8]);
            acc[tt] = __builtin_amdgcn_mfma_f32_16x16x32_bf16(af, bf, acc[tt], 0, 0, 0);
        }
        __syncthreads();
    }
    int rbase = mb + w * 16 + lg * 4;
    #pragma unroll
    for (int tt = 0; tt < 4; tt++) {
        int n = nb + tt * 16 + li;
        int h = n >> 6, d = n & 63;
        #pragma unroll
        for (int r = 0; r < 4; r++) {
            int m = rbase + r;
            int b = m >> 11, s = m & 2047;
            outp[(((size_t)(b * NHEAD + h)) * SEQ + s) * HDIM + d] = f2bf(acc[tt][r]);
        }
    }
}

// ---------------- causal flash attention (swapped QK^T, 32x32 MFMA) ----------------
// Q,K,V: [b*h][s][64] bf16 -> ctx [b][s][h*64+d] bf16
__device__ __forceinline__ void kstore(u16 (*kb)[68], u16 (*vb)[68],
                                       int krow, int kpart, int w, int lane,
                                       bfx8 k0, bfx8 k1, bfx8 v0, bfx8 v1) {
    u16* kd = &kb[krow][kpart * 16];
    bfx4 t0 = {k0[0], k0[1], k0[2], k0[3]};
    bfx4 t1 = {k0[4], k0[5], k0[6], k0[7]};
    bfx4 t2 = {k1[0], k1[1], k1[2], k1[3]};
    bfx4 t3 = {k1[4], k1[5], k1[6], k1[7]};
    *reinterpret_cast<bfx4*>(kd)      = t0;
    *reinterpret_cast<bfx4*>(kd + 4)  = t1;
    *reinterpret_cast<bfx4*>(kd + 8)  = t2;
    *reinterpret_cast<bfx4*>(kd + 12) = t3;
    #pragma unroll
    for (int i = 0; i < 8; i++) vb[w * 16 + i][lane] = (u16)v0[i];
    #pragma unroll
    for (int i = 0; i < 8; i++) vb[w * 16 + 8 + i][lane] = (u16)v1[i];
}

__global__ __launch_bounds__(256) void k_attn(const u16* __restrict__ qkv,
                                              u16* __restrict__ ctx) {
    __shared__ u16 kbuf[2][64][68];   // K tile  [kv][d], pad 4 -> 2-way banks on b64 reads
    __shared__ u16 vbuf[2][64][68];   // V tile transposed [d][kv], pad 4
    const u16* Q  = qkv;
    const u16* Kp = qkv + (size_t)M_TOT * D_OUT;
    const u16* Vp = Kp + (size_t)M_TOT * D_OUT;

    // XCD-grouped mapping: 4 bh per XCD (K/V working set 2MB < 4MB L2),
    // heavy q-blocks dispatched first within each group.
    const int g   = blockIdx.x;            // 0..511
    const int xcd = g & 7;
    const int wi  = g >> 3;                // 0..63
    const int bh  = xcd * 4 + (wi & 3);    // 0..31
    const int qi  = wi >> 2;               // 0..15
    const int qb  = (15 - qi) * 128;

    const size_t base = (size_t)bh * SEQ * HDIM;
    const int t = threadIdx.x, lane = t & 63, w = t >> 6;
    const int l31 = lane & 31, hi = lane >> 5;
    const int qwb = qb + w * 32;
    const int qg  = qwb + l31;             // this lane's q row (S^T column)

    // Q fragments (B-operand): col=lane&31=q, k = 16*dc + 8*hi + j
    bfx8 qf[4];
    #pragma unroll
    for (int dc = 0; dc < 4; dc++)
        qf[dc] = *reinterpret_cast<const bfx8*>(&Q[base + (size_t)qg * HDIM + dc * 16 + hi * 8]);

    fx16 cacc[2];
    #pragma unroll
    for (int dt = 0; dt < 2; dt++)
        #pragma unroll
        for (int r = 0; r < 16; r++) cacc[dt][r] = 0.f;

    float mrun = -1e30f, lsum = 0.f;
    const int nt = qb / 64 + 2;

    const int krow = t >> 2, kpart = t & 3;   // K staging: row, 32B part
    bfx8 kreg0, kreg1, vreg0, vreg1;

    {   // prologue: tile 0
        const size_t kb_ = base + (size_t)krow * HDIM + kpart * 16;
        kreg0 = *reinterpret_cast<const bfx8*>(&Kp[kb_]);
        kreg1 = *reinterpret_cast<const bfx8*>(&Kp[kb_ + 8]);
        const size_t vb_ = base + (size_t)lane * HDIM + w * 16;
        vreg0 = *reinterpret_cast<const bfx8*>(&Vp[vb_]);
        vreg1 = *reinterpret_cast<const bfx8*>(&Vp[vb_ + 8]);
        kstore(kbuf[0], vbuf[0], krow, kpart, w, lane, kreg0, kreg1, vreg0, vreg1);
    }
    __syncthreads();

    for (int ti = 0; ti < nt; ti++) {
        const int kvb = ti * 64;
        const int bi = ti & 1;
        if (ti + 1 < nt) {   // issue next tile's global loads early (T14)
            const int nb = (ti + 1) * 64;
            const size_t kb_ = base + (size_t)(nb + krow) * HDIM + kpart * 16;
            kreg0 = *reinterpret_cast<const bfx8*>(&Kp[kb_]);
            kreg1 = *reinterpret_cast<const bfx8*>(&Kp[kb_ + 8]);
            const size_t vb_ = base + (size_t)(nb + lane) * HDIM + w * 16;
            vreg0 = *reinterpret_cast<const bfx8*>(&Vp[vb_]);
            vreg1 = *reinterpret_cast<const bfx8*>(&Vp[vb_ + 8]);
        }
        if (kvb <= qwb + 31) {   // wave-level causal skip
            // ---- S^T = K · Q^T : rows=kv, cols=q ----
            fx16 sc[2];
            #pragma unroll
            for (int s = 0; s < 2; s++) {
                #pragma unroll
                for (int r = 0; r < 16; r++) sc[s][r] = 0.f;
                #pragma unroll
                for (int dc = 0; dc < 4; dc++) {
                    bfx8 af = ld8(&kbuf[bi][s * 32 + l31][dc * 16 + hi * 8]);
                    sc[s] = __builtin_amdgcn_mfma_f32_32x32x16_bf16(af, qf[dc], sc[s], 0, 0, 0);
                }
            }
            // scale + causal mask (only diagonal tile needs the mask)
            if (kvb + 63 > qwb) {
                #pragma unroll
                for (int s = 0; s < 2; s++)
                    #pragma unroll
                    for (int r = 0; r < 16; r++) {
                        int kvg = kvb + s * 32 + (r & 3) + 8 * (r >> 2) + 4 * hi;
                        float v = sc[s][r] * 0.125f;
                        sc[s][r] = (kvg > qg) ? -1e30f : v;
                    }
            } else {
                #pragma unroll
                for (int s = 0; s < 2; s++)
                    #pragma unroll
                    for (int r = 0; r < 16; r++) sc[s][r] *= 0.125f;
            }
            // row max: in-lane tree + one cross-half swap
            float a[16];
            #pragma unroll
            for (int r = 0; r < 16; r++) a[r] = fmaxf(sc[0][r], sc[1][r]);
            #pragma unroll
            for (int off = 8; off; off >>= 1)
                #pragma unroll
                for (int r = 0; r < off; r++) a[r] = fmaxf(a[r], a[r + off]);
            float mx = fmaxf(a[0], __shfl_xor(a[0], 32));
            // defer-max rescale (T13, THR=8 nat-log units)
            if (!__all(mx <= mrun + 8.f)) {
                float newm = fmaxf(mrun, mx);
                float corr = __expf(mrun - newm);
                mrun = newm;
                lsum *= corr;
                #pragma unroll
                for (int dt = 0; dt < 2; dt++)
                    #pragma unroll
                    for (int r = 0; r < 16; r++) cacc[dt][r] *= corr;
            }
            float ps0 = 0.f, ps1 = 0.f;
            #pragma unroll
            for (int s = 0; s < 2; s++)
                #pragma unroll
                for (int r = 0; r < 16; r++) {
                    float p = __expf(sc[s][r] - mrun);
                    sc[s][r] = p;
                    if (r & 1) ps1 += p; else ps0 += p;
                }
            lsum += ps0 + ps1;
            // ---- pack P to bf16, lane-pair exchange, PV ----
            #pragma unroll
            for (int c = 0; c < 4; c++) {           // kv chunk of 16
                const int s = c >> 1, rb = (c & 1) * 8;
                u32 a0 = cvtpk(sc[s][rb + 0], sc[s][rb + 1]);
                u32 a1 = cvtpk(sc[s][rb + 2], sc[s][rb + 3]);
                u32 b0 = cvtpk(sc[s][rb + 4], sc[s][rb + 5]);
                u32 b1 = cvtpk(sc[s][rb + 6], sc[s][rb + 7]);
                u32 X0 = hi ? a0 : b0, X1 = hi ? a1 : b1;
                u32 Y0 = (u32)__shfl_xor((int)X0, 32);
                u32 Y1 = (u32)__shfl_xor((int)X1, 32);
                uint4 pw;
                pw.x = hi ? Y0 : a0;
                pw.y = hi ? Y1 : a1;
                pw.z = hi ? b0 : Y0;
                pw.w = hi ? b1 : Y1;
                bfx8 pf = __builtin_bit_cast(bfx8, pw);
                #pragma unroll
                for (int dt = 0; dt < 2; dt++) {
                    bfx8 vf = ld8(&vbuf[bi][dt * 32 + l31][c * 16 + hi * 8]);
                    cacc[dt] = __builtin_amdgcn_mfma_f32_32x32x16_bf16(pf, vf, cacc[dt], 0, 0, 0);
                }
            }
        }
        if (ti + 1 < nt)
            kstore(kbuf[(ti + 1) & 1], vbuf[(ti + 1) & 1], krow, kpart, w, lane,
                   kreg0, kreg1, vreg0, vreg1);
        __syncthreads();
    }

    // epilogue: 1/l per q, redistributed by shfl; write ctx
    float ltot = lsum + __shfl_xor(lsum, 32);
    float linv = 1.0f / ltot;
    const int b = bh >> 4, h = bh & 15;
    #pragma unroll
    for (int r = 0; r < 16; r++) {
        const int qpat = (r & 3) + 8 * (r >> 2) + 4 * hi;
        float rl = __shfl(linv, qpat);
        const int q = qwb + qpat;
        #pragma unroll
        for (int dt = 0; dt < 2; dt++)
            ctx[((size_t)(b * SEQ + q)) * D_OUT + h * HDIM + dt * 32 + l31] =
                f2bf(cacc[dt][r] * rl);
    }
}

// ---------------- output projection + bias ----------------
__global__ __launch_bounds__(256) void k_oproj(const u16* __restrict__ cb,
                                               const u16* __restrict__ wot,
                                               const float* __restrict__ bo,
                                               float* __restrict__ out) {
    __shared__ u16 aL[64][32];
    __shared__ u16 bL[64][32];
    const int K = D_OUT;
    int nb = blockIdx.x * 64, mb = blockIdx.y * 64;
    int t = threadIdx.x, lane = t & 63, w = t >> 6;
    int lg = lane >> 4, li = lane & 15;
    int srow = t >> 2, schunk = (t & 3) * 8;
    fx4 acc[4] = {{0,0,0,0},{0,0,0,0},{0,0,0,0},{0,0,0,0}};
    for (int kb = 0; kb < K; kb += 32) {
        *reinterpret_cast<bfx8*>(&aL[srow][schunk]) =
            *reinterpret_cast<const bfx8*>(&cb[(size_t)(mb + srow) * K + kb + schunk]);
        *reinterpret_cast<bfx8*>(&bL[srow][schunk]) =
            *reinterpret_cast<const bfx8*>(&wot[(size_t)(nb + srow) * K + kb + schunk]);
        __syncthreads();
        bfx8 af = *reinterpret_cast<const bfx8*>(&aL[w * 16 + li][lg * 8]);
        #pragma unroll
        for (int tt = 0; tt < 4; tt++) {
            bfx8 bf = *reinterpret_cast<const bfx8*>(&bL[tt * 16 + li][lg * 8]);
            acc[tt] = __builtin_amdgcn_mfma_f32_16x16x32_bf16(af, bf, acc[tt], 0, 0, 0);
        }
        __syncthreads();
    }
    int rbase = mb + w * 16 + lg * 4;
    #pragma unroll
    for (int tt = 0; tt < 4; tt++) {
        int n = nb + tt * 16 + li;
        float bias = bo[n];
        #pragma unroll
        for (int r = 0; r < 4; r++) {
            int m = rbase + r;
            out[(size_t)m * D_OUT + n] = acc[tt][r] + bias;
        }
    }
}

extern "C" void kernel_launch(void* const* d_in, const int* in_sizes, int n_in,
                              void* d_out, int out_size, void* d_ws, size_t ws_size,
                              hipStream_t stream) {
    const float* x  = (const float*)d_in[0];
    const float* Wq = (const float*)d_in[1];
    const float* Wk = (const float*)d_in[2];
    const float* Wv = (const float*)d_in[3];
    const float* Wo = (const float*)d_in[4];
    const float* bo = (const float*)d_in[5];
    float* out = (float*)d_out;

    char* ws = (char*)d_ws;
    u16* xb   = (u16*)(ws);                    //  8 MiB: x bf16
    u16* wt   = (u16*)(ws + (8u << 20));       //  8 MiB: W transposed bf16
    u16* qkvb = (u16*)(ws + (16u << 20));      // 24 MiB: Q,K,V [b*h][s][d] bf16
    u16* ctxb = (u16*)(ws + (40u << 20));      //  8 MiB: ctx bf16

    k_conv_x <<<2048, 256, 0, stream>>>(x, xb);
    k_conv_wt<<<dim3(32, 32, 4), 256, 0, stream>>>(Wq, Wk, Wv, Wo, wt);
    k_qkv    <<<dim3(D_OUT / 64, M_TOT / 64, 3), 256, 0, stream>>>(xb, wt, qkvb);
    k_attn   <<<dim3(512), 256, 0, stream>>>(qkvb, ctxb);
    k_oproj  <<<dim3(D_OUT / 64, M_TOT / 64), 256, 0, stream>>>(
        ctxb, wt + (size_t)3 * D_IN * D_OUT, bo, out);
}

// Round 4
// 136.272 us; speedup vs baseline: 2.3931x; 1.1969x over previous
//
#include <hip/hip_runtime.h>
#include <hip/hip_bf16.h>
#include <stdint.h>

#define D_IN   1024
#define D_OUT  1024
#define NHEAD  16
#define HDIM   64
#define SEQ    2048
#define BATCH  2
#define M_TOT  (BATCH*SEQ)   // 4096

typedef __attribute__((ext_vector_type(8)))  short bfx8;   // 8 bf16
typedef __attribute__((ext_vector_type(4)))  short bfx4;   // 4 bf16
typedef __attribute__((ext_vector_type(4)))  float fx4;
typedef __attribute__((ext_vector_type(16))) float fx16;
typedef unsigned short u16;
typedef unsigned int   u32;

__device__ __forceinline__ u16 f2bf(float f) {
    u32 u = __builtin_bit_cast(u32, f);
    u32 r = (u + 0x7FFFu + ((u >> 16) & 1u)) >> 16;   // RNE
    return (u16)r;
}

__device__ __forceinline__ u32 cvtpk(float lo, float hi) {
    u32 r;
    asm("v_cvt_pk_bf16_f32 %0, %1, %2" : "=v"(r) : "v"(lo), "v"(hi));
    return r;
}

__device__ __forceinline__ bfx8 ld8(const u16* p) {      // two 8B LDS reads
    bfx4 a = *reinterpret_cast<const bfx4*>(p);
    bfx4 b = *reinterpret_cast<const bfx4*>(p + 4);
    bfx8 r = {a[0], a[1], a[2], a[3], b[0], b[1], b[2], b[3]};
    return r;
}

// async global -> LDS, 16B per lane. LDS dest = wave-uniform base + lane*16.
__device__ __forceinline__ void gload16(const u16* g, u16* l) {
    __builtin_amdgcn_global_load_lds(
        (const __attribute__((address_space(1))) void*)g,
        (__attribute__((address_space(3))) void*)l, 16, 0, 0);
}

// ---------------- x fp32 -> bf16 ----------------
__global__ void k_conv_x(const float* __restrict__ x, u16* __restrict__ xb) {
    int i = blockIdx.x * 256 + threadIdx.x;
    const float4* s = reinterpret_cast<const float4*>(x);
    float4 a = s[2*i], b = s[2*i+1];
    uint4 o;
    o.x = (u32)f2bf(a.x) | ((u32)f2bf(a.y) << 16);
    o.y = (u32)f2bf(a.z) | ((u32)f2bf(a.w) << 16);
    o.z = (u32)f2bf(b.x) | ((u32)f2bf(b.y) << 16);
    o.w = (u32)f2bf(b.z) | ((u32)f2bf(b.w) << 16);
    reinterpret_cast<uint4*>(xb)[i] = o;
}

// ------------- W fp32 -> bf16, transposed (Wt[n][k] = W[k][n]) -------------
__global__ void k_conv_wt(const float* __restrict__ Wq, const float* __restrict__ Wk,
                          const float* __restrict__ Wv, const float* __restrict__ Wo,
                          u16* __restrict__ wt) {
    __shared__ float tile[32][33];
    int wsel = blockIdx.z;
    const float* W = (wsel == 0) ? Wq : (wsel == 1) ? Wk : (wsel == 2) ? Wv : Wo;
    u16* dst = wt + (size_t)wsel * D_IN * D_OUT;
    int r0 = blockIdx.y * 32, c0 = blockIdx.x * 32;
    int tx = threadIdx.x & 31, ty = threadIdx.x >> 5;
    #pragma unroll
    for (int k = 0; k < 4; k++) {
        int i = ty + k * 8;
        tile[i][tx] = W[(size_t)(r0 + i) * D_OUT + c0 + tx];
    }
    __syncthreads();
    #pragma unroll
    for (int k = 0; k < 4; k++) {
        int i = ty + k * 8;
        dst[(size_t)(c0 + i) * D_IN + r0 + tx] = f2bf(tile[tx][i]);
    }
}

// ---------------- 128x128 GEMM (m97 structure) ----------------
// A [M][1024] bf16, Bt [N][1024] bf16 (rows = output cols).
// MODE 0: qkv fused (N=3072): write bf16 head-split [proj][b*h][s][d]
// MODE 1: oproj: write f32 out[m][n] = acc + bias[n]
template<int MODE>
__global__ __launch_bounds__(256) void k_gemm128(const u16* __restrict__ A,
                                                 const u16* __restrict__ Bt,
                                                 const float* __restrict__ bias,
                                                 u16* __restrict__ outb,
                                                 float* __restrict__ outf) {
    __shared__ u16 aL[128][32];
    __shared__ u16 bL[128][32];
    const int K = 1024;
    const int nb = blockIdx.x * 128, mb = blockIdx.y * 128;
    const int t = threadIdx.x, lane = t & 63, w = t >> 6;
    const int wr = w >> 1, wc = w & 1;
    const int li = lane & 15, lg = lane >> 4;
    const int srow = lane >> 2, schunk = (lane & 3) * 8;   // staging row/chunk in 16-row slab

    fx4 acc[4][4];
    #pragma unroll
    for (int i = 0; i < 4; i++)
        #pragma unroll
        for (int j = 0; j < 4; j++) acc[i][j] = fx4{0.f, 0.f, 0.f, 0.f};

    const u16* aBase = A  + (size_t)(mb + w * 32 + srow) * K + schunk;
    const u16* bBase = Bt + (size_t)(nb + w * 32 + srow) * K + schunk;

    for (int kb = 0; kb < K; kb += 32) {
        #pragma unroll
        for (int c = 0; c < 2; c++) {
            gload16(aBase + (size_t)c * 16 * K + kb, &aL[w * 32 + c * 16][0]);
            gload16(bBase + (size_t)c * 16 * K + kb, &bL[w * 32 + c * 16][0]);
        }
        __syncthreads();
        bfx8 af[4], bf[4];
        #pragma unroll
        for (int mi = 0; mi < 4; mi++)
            af[mi] = *reinterpret_cast<const bfx8*>(&aL[wr * 64 + mi * 16 + li][lg * 8]);
        #pragma unroll
        for (int ni = 0; ni < 4; ni++)
            bf[ni] = *reinterpret_cast<const bfx8*>(&bL[wc * 64 + ni * 16 + li][lg * 8]);
        #pragma unroll
        for (int mi = 0; mi < 4; mi++)
            #pragma unroll
            for (int ni = 0; ni < 4; ni++)
                acc[mi][ni] = __builtin_amdgcn_mfma_f32_16x16x32_bf16(af[mi], bf[ni], acc[mi][ni], 0, 0, 0);
        __syncthreads();
    }

    #pragma unroll
    for (int mi = 0; mi < 4; mi++) {
        #pragma unroll
        for (int ni = 0; ni < 4; ni++) {
            const int n = nb + wc * 64 + ni * 16 + li;
            const int m0 = mb + wr * 64 + mi * 16 + lg * 4;
            if (MODE == 0) {
                const int proj = n >> 10, h = (n >> 6) & 15, d = n & 63;
                u16* op = outb + (size_t)proj * M_TOT * D_OUT;   // FIX: proj stride is M_TOT*D_OUT
                #pragma unroll
                for (int r = 0; r < 4; r++) {
                    const int m = m0 + r, b = m >> 11, s = m & 2047;
                    op[((size_t)(b * NHEAD + h) * SEQ + s) * HDIM + d] = f2bf(acc[mi][ni][r]);
                }
            } else {
                const float bv = bias[n];
                #pragma unroll
                for (int r = 0; r < 4; r++)
                    outf[(size_t)(m0 + r) * D_OUT + n] = acc[mi][ni][r] + bv;
            }
        }
    }
}

// ---------------- causal flash attention (swapped QK^T, 32x32 MFMA) ----------------
// 128 threads = 2 waves, 64 q-rows per block, KVBLK=64, double-buffered.
__device__ __forceinline__ void kvstore(u16 (*kb)[68], u16 (*vb)[68],
                                        int krow, int khalf, int w, int lane,
                                        const bfx8* kr, const bfx8* vr) {
    u16* kd = &kb[krow][khalf * 32];
    #pragma unroll
    for (int j = 0; j < 4; j++) {
        bfx4 lo = {kr[j][0], kr[j][1], kr[j][2], kr[j][3]};
        bfx4 hi = {kr[j][4], kr[j][5], kr[j][6], kr[j][7]};
        *reinterpret_cast<bfx4*>(kd + j * 8)     = lo;
        *reinterpret_cast<bfx4*>(kd + j * 8 + 4) = hi;
    }
    #pragma unroll
    for (int j = 0; j < 4; j++)
        #pragma unroll
        for (int i = 0; i < 8; i++)
            vb[w * 32 + j * 8 + i][lane] = (u16)vr[j][i];
}

__global__ __launch_bounds__(128) void k_attn(const u16* __restrict__ qkv,
                                              u16* __restrict__ ctx) {
    __shared__ u16 kbuf[2][64][68];   // K tile [kv][d], +4 pad
    __shared__ u16 vbuf[2][64][68];   // V^T tile [d][kv], +4 pad
    const u16* Q  = qkv;
    const u16* Kp = qkv + (size_t)M_TOT * D_OUT;
    const u16* Vp = Kp + (size_t)M_TOT * D_OUT;

    // XCD-grouped: 4 bh per XCD; heavy q-blocks first.
    const int g   = blockIdx.x;            // 0..1023
    const int xcd = g & 7;
    const int wi  = g >> 3;                // 0..127
    const int bh  = xcd * 4 + (wi & 3);    // 0..31
    const int qi  = wi >> 2;               // 0..31
    const int qb  = (31 - qi) * 64;

    const size_t base = (size_t)bh * SEQ * HDIM;
    const int t = threadIdx.x, lane = t & 63, w = t >> 6;   // w in 0..1
    const int l31 = lane & 31, hi = lane >> 5;
    const int qwb = qb + w * 32;
    const int qg  = qwb + l31;             // this lane's q row

    bfx8 qf[4];
    #pragma unroll
    for (int dc = 0; dc < 4; dc++)
        qf[dc] = *reinterpret_cast<const bfx8*>(&Q[base + (size_t)qg * HDIM + dc * 16 + hi * 8]);

    fx16 cacc[2];
    #pragma unroll
    for (int dt = 0; dt < 2; dt++)
        #pragma unroll
        for (int r = 0; r < 16; r++) cacc[dt][r] = 0.f;

    float mrun = -1e30f, lsum = 0.f;
    const int nt = qb / 64 + 1;

    const int krow = t >> 1, khalf = t & 1;   // K staging: row 0..63, 64B half
    bfx8 kr[4], vr[4];

    {   // prologue: tile 0
        const u16* kp = &Kp[base + (size_t)krow * HDIM + khalf * 32];
        const u16* vp = &Vp[base + (size_t)lane * HDIM + w * 32];
        #pragma unroll
        for (int j = 0; j < 4; j++) {
            kr[j] = *reinterpret_cast<const bfx8*>(kp + j * 8);
            vr[j] = *reinterpret_cast<const bfx8*>(vp + j * 8);
        }
        kvstore(kbuf[0], vbuf[0], krow, khalf, w, lane, kr, vr);
    }
    __syncthreads();

    for (int ti = 0; ti < nt; ti++) {
        const int kvb = ti * 64;
        const int bi = ti & 1;
        if (ti + 1 < nt) {   // issue next tile's global loads early (T14)
            const int nbv = (ti + 1) * 64;
            const u16* kp = &Kp[base + (size_t)(nbv + krow) * HDIM + khalf * 32];
            const u16* vp = &Vp[base + (size_t)(nbv + lane) * HDIM + w * 32];
            #pragma unroll
            for (int j = 0; j < 4; j++) {
                kr[j] = *reinterpret_cast<const bfx8*>(kp + j * 8);
                vr[j] = *reinterpret_cast<const bfx8*>(vp + j * 8);
            }
        }
        // ---- S^T = K · Q^T : rows=kv, cols=q ----
        fx16 sc[2];
        __builtin_amdgcn_s_setprio(1);
        #pragma unroll
        for (int s = 0; s < 2; s++) {
            #pragma unroll
            for (int r = 0; r < 16; r++) sc[s][r] = 0.f;
            #pragma unroll
            for (int dc = 0; dc < 4; dc++) {
                bfx8 af = ld8(&kbuf[bi][s * 32 + l31][dc * 16 + hi * 8]);
                sc[s] = __builtin_amdgcn_mfma_f32_32x32x16_bf16(af, qf[dc], sc[s], 0, 0, 0);
            }
        }
        __builtin_amdgcn_s_setprio(0);
        // scale + causal mask (diagonal tile only)
        if (kvb + 63 > qwb) {
            #pragma unroll
            for (int s = 0; s < 2; s++)
                #pragma unroll
                for (int r = 0; r < 16; r++) {
                    int kvg = kvb + s * 32 + (r & 3) + 8 * (r >> 2) + 4 * hi;
                    float v = sc[s][r] * 0.125f;
                    sc[s][r] = (kvg > qg) ? -1e30f : v;
                }
        } else {
            #pragma unroll
            for (int s = 0; s < 2; s++)
                #pragma unroll
                for (int r = 0; r < 16; r++) sc[s][r] *= 0.125f;
        }
        // row max: in-lane tree + one cross-half swap
        float a[16];
        #pragma unroll
        for (int r = 0; r < 16; r++) a[r] = fmaxf(sc[0][r], sc[1][r]);
        #pragma unroll
        for (int off = 8; off; off >>= 1)
            #pragma unroll
            for (int r = 0; r < off; r++) a[r] = fmaxf(a[r], a[r + off]);
        float mx = fmaxf(a[0], __shfl_xor(a[0], 32));
        // defer-max rescale (T13)
        if (!__all(mx <= mrun + 8.f)) {
            float newm = fmaxf(mrun, mx);
            float corr = __expf(mrun - newm);
            mrun = newm;
            lsum *= corr;
            #pragma unroll
            for (int dt = 0; dt < 2; dt++)
                #pragma unroll
                for (int r = 0; r < 16; r++) cacc[dt][r] *= corr;
        }
        float ps = 0.f;
        #pragma unroll
        for (int s = 0; s < 2; s++)
            #pragma unroll
            for (int r = 0; r < 16; r++) {
                float p = __expf(sc[s][r] - mrun);
                sc[s][r] = p;
                ps += p;
            }
        lsum += ps;
        // ---- pack P to bf16, lane-pair exchange, PV ----
        #pragma unroll
        for (int c = 0; c < 4; c++) {           // kv chunk of 16
            const int s = c >> 1, rb = (c & 1) * 8;
            u32 a0 = cvtpk(sc[s][rb + 0], sc[s][rb + 1]);
            u32 a1 = cvtpk(sc[s][rb + 2], sc[s][rb + 3]);
            u32 b0 = cvtpk(sc[s][rb + 4], sc[s][rb + 5]);
            u32 b1 = cvtpk(sc[s][rb + 6], sc[s][rb + 7]);
            u32 X0 = hi ? a0 : b0, X1 = hi ? a1 : b1;
            u32 Y0 = (u32)__shfl_xor((int)X0, 32);
            u32 Y1 = (u32)__shfl_xor((int)X1, 32);
            uint4 pw;
            pw.x = hi ? Y0 : a0;
            pw.y = hi ? Y1 : a1;
            pw.z = hi ? b0 : Y0;
            pw.w = hi ? b1 : Y1;
            bfx8 pf = __builtin_bit_cast(bfx8, pw);
            __builtin_amdgcn_s_setprio(1);
            #pragma unroll
            for (int dt = 0; dt < 2; dt++) {
                bfx8 vf = ld8(&vbuf[bi][dt * 32 + l31][c * 16 + hi * 8]);
                cacc[dt] = __builtin_amdgcn_mfma_f32_32x32x16_bf16(pf, vf, cacc[dt], 0, 0, 0);
            }
            __builtin_amdgcn_s_setprio(0);
        }
        if (ti + 1 < nt)
            kvstore(kbuf[(ti + 1) & 1], vbuf[(ti + 1) & 1], krow, khalf, w, lane, kr, vr);
        __syncthreads();
    }

    // epilogue
    float ltot = lsum + __shfl_xor(lsum, 32);
    float linv = 1.0f / ltot;
    const int b = bh >> 4, h = bh & 15;
    #pragma unroll
    for (int r = 0; r < 16; r++) {
        const int qpat = (r & 3) + 8 * (r >> 2) + 4 * hi;
        float rl = __shfl(linv, qpat);
        const int q = qwb + qpat;
        #pragma unroll
        for (int dt = 0; dt < 2; dt++)
            ctx[((size_t)(b * SEQ + q)) * D_OUT + h * HDIM + dt * 32 + l31] =
                f2bf(cacc[dt][r] * rl);
    }
}

extern "C" void kernel_launch(void* const* d_in, const int* in_sizes, int n_in,
                              void* d_out, int out_size, void* d_ws, size_t ws_size,
                              hipStream_t stream) {
    const float* x  = (const float*)d_in[0];
    const float* Wq = (const float*)d_in[1];
    const float* Wk = (const float*)d_in[2];
    const float* Wv = (const float*)d_in[3];
    const float* Wo = (const float*)d_in[4];
    const float* bo = (const float*)d_in[5];
    float* out = (float*)d_out;

    char* ws = (char*)d_ws;
    u16* xb   = (u16*)(ws);                    //  8 MiB: x bf16
    u16* wt   = (u16*)(ws + (8u << 20));       //  8 MiB: W transposed bf16
    u16* qkvb = (u16*)(ws + (16u << 20));      // 24 MiB: Q,K,V [b*h][s][d] bf16
    u16* ctxb = (u16*)(ws + (40u << 20));      //  8 MiB: ctx bf16

    k_conv_x <<<2048, 256, 0, stream>>>(x, xb);
    k_conv_wt<<<dim3(32, 32, 4), 256, 0, stream>>>(Wq, Wk, Wv, Wo, wt);
    k_gemm128<0><<<dim3(24, 32), 256, 0, stream>>>(xb, wt, nullptr, qkvb, nullptr);
    k_attn   <<<dim3(1024), 128, 0, stream>>>(qkvb, ctxb);
    k_gemm128<1><<<dim3(8, 32), 256, 0, stream>>>(
        ctxb, wt + (size_t)3 * D_IN * D_OUT, bo, nullptr, out);
}